// Round 8
// baseline (112.851 us; speedup 1.0000x reference)
//
#include <hip/hip_runtime.h>

#define NN 64
#define HH 512

typedef _Float16 h8 __attribute__((ext_vector_type(8)));
typedef float    fx4 __attribute__((ext_vector_type(4)));

#define MFMA __builtin_amdgcn_mfma_f32_16x16x32_f16

// cvt 16 fp32 (4 float4) -> 16 fp16 -> LDS (two h8 stores)
__device__ __forceinline__ void cvt_store16(_Float16* d, const float4* p) {
    h8 h0, h1;
    h0[0]=(_Float16)p[0].x; h0[1]=(_Float16)p[0].y; h0[2]=(_Float16)p[0].z; h0[3]=(_Float16)p[0].w;
    h0[4]=(_Float16)p[1].x; h0[5]=(_Float16)p[1].y; h0[6]=(_Float16)p[1].z; h0[7]=(_Float16)p[1].w;
    h1[0]=(_Float16)p[2].x; h1[1]=(_Float16)p[2].y; h1[2]=(_Float16)p[2].z; h1[3]=(_Float16)p[2].w;
    h1[4]=(_Float16)p[3].x; h1[5]=(_Float16)p[3].y; h1[6]=(_Float16)p[3].z; h1[7]=(_Float16)p[3].w;
    *(h8*)d = h0; *((h8*)d + 1) = h1;
}

// WG = 256 thr (4 waves), node n = bid&63, batch rows [tile*128, +128), wave owns 32 rows.
// Weights staged fp32->fp16 into dbuf LDS chunks (coalesced), MFMA 16x16x32_f16.
// Stage C folds xn*W3[:,64+n] + b3 into a 5th K-step MFMA.
// NOTE: verbatim re-submission of the Round-3 kernel — the only version that
// passed the FULL harness (correctness + graph replay + tripwire). Rounds 4-7
// variants (transposed C/D, shfl epilogue) exhibit run-to-run nondeterminism.
__global__ __launch_bounds__(256, 2)
void causal_mfma3(const float* __restrict__ x,  const float* __restrict__ W1,
                  const float* __restrict__ W2, const float* __restrict__ W3,
                  const float* __restrict__ b3, const float* __restrict__ W4,
                  const float* __restrict__ b4, float* __restrict__ out)
{
    __shared__ __align__(16) char smem[61952];
    _Float16* W1c  = (_Float16*)smem;          // [2][64][72]  (stage C reuses as W3 dbuf)
    _Float16* W2c  = W1c + 2 * 4608;           // [2][64][72]
    _Float16* priv = W2c + 2 * 4608;           // [4 waves][32][72]
    float*    w3cs = (float*)(smem + 55296);   // [512]  W3[:,64+n]
    float*    b3s  = w3cs + 512;               // [512]
    float*    w4s  = b3s + 512;                // [512]
    float*    xns  = w4s + 512;                // [128]

    const int tid  = threadIdx.x;
    const int bid  = blockIdx.x;
    const int n    = bid & 63;                 // same-node WGs -> same bid%8 -> same XCD
    const int tile = bid >> 6;                 // 0..7
    const int lane = tid & 63;
    const int pos  = lane & 15;
    const int quad = lane >> 4;
    const int wv   = __builtin_amdgcn_readfirstlane(tid >> 6);   // 0..3
    const int row0 = tile * 128;
    const int wrow = wv << 5;                  // wave's 32-row base within WG

    const float* W1n = W1 + (size_t)n * HH * NN;
    const float* W2n = W2 + (size_t)n * NN * HH;
    const float* W3n = W3 + (size_t)n * HH * 128;

    const int trow = tid >> 2;                 // staging row 0..63
    const int tcol = (tid & 3) << 4;           // 0,16,32,48

    // ---- prologue: chunk-0 weight staging + scalar arrays + xn + Xm A-frags ----
    {
        float4 p1[4], p2[4];
        #pragma unroll
        for (int q = 0; q < 4; ++q) p1[q] = *(const float4*)(W1n + trow * 64 + tcol + q * 4);
        #pragma unroll
        for (int q = 0; q < 4; ++q) p2[q] = *(const float4*)(W2n + (size_t)trow * HH + tcol + q * 4);
        #pragma unroll
        for (int k = 0; k < 2; ++k) {
            const int h = tid + k * 256;
            w3cs[h] = W3n[(size_t)h * 128 + 64 + n];
            b3s[h]  = b3[n * HH + h];
            w4s[h]  = W4[n * HH + h];
        }
        if (tid < 128) xns[tid] = x[(size_t)(row0 + tid) * NN + n];
        cvt_store16(W1c + trow * 72 + tcol, p1);
        cvt_store16(W2c + trow * 72 + tcol, p2);
    }

    // Xm A-fragments (own element zeroed) — chunk-invariant
    h8 aX[2][2];
    #pragma unroll
    for (int mt = 0; mt < 2; ++mt)
        #pragma unroll
        for (int ks = 0; ks < 2; ++ks) {
            const float* p = x + (size_t)(row0 + wrow + mt * 16 + pos) * NN + ks * 32 + quad * 8;
            float4 a = *(const float4*)p, bq = *(const float4*)(p + 4);
            float v[8] = {a.x, a.y, a.z, a.w, bq.x, bq.y, bq.z, bq.w};
            const int base = ks * 32 + quad * 8;
            #pragma unroll
            for (int j = 0; j < 8; ++j) if (base + j == n) v[j] = 0.f;
            h8 h;
            #pragma unroll
            for (int j = 0; j < 8; ++j) h[j] = (_Float16)v[j];
            aX[mt][ks] = h;
        }
    __syncthreads();

    _Float16* P = priv + wv * 2304;            // own 32x72 buffer

    // ---- fused stages A+B over 8 h-chunks of 64 ----
    fx4 acc2[2][4] = {};                       // r1: [mt][m-tile]
    for (int c = 0; c < 8; ++c) {
        const int cb = c & 1;
        float4 p1[4], p2[4];
        if (c < 7) {
            const int hb1 = (c + 1) << 6;
            #pragma unroll
            for (int q = 0; q < 4; ++q) p1[q] = *(const float4*)(W1n + (hb1 + trow) * 64 + tcol + q * 4);
            #pragma unroll
            for (int q = 0; q < 4; ++q) p2[q] = *(const float4*)(W2n + (size_t)trow * HH + hb1 + tcol + q * 4);
        }
        // stage A: h1 chunk = Xm @ W1chunk^T
        const _Float16* W1L = W1c + cb * 4608;
        fx4 accA[2][4] = {};
        #pragma unroll
        for (int ks = 0; ks < 2; ++ks)
            #pragma unroll
            for (int nt = 0; nt < 4; ++nt) {
                h8 bf = *(const h8*)(W1L + (nt * 16 + pos) * 72 + ks * 32 + quad * 8);
                accA[0][nt] = MFMA(aX[0][ks], bf, accA[0][nt], 0, 0, 0);
                accA[1][nt] = MFMA(aX[1][ks], bf, accA[1][nt], 0, 0, 0);
            }
        // h1 -> own LDS (relu, fp16), then A-frags for stage B
        #pragma unroll
        for (int mt = 0; mt < 2; ++mt)
            #pragma unroll
            for (int nt = 0; nt < 4; ++nt)
                #pragma unroll
                for (int r = 0; r < 4; ++r)
                    P[(mt * 16 + quad * 4 + r) * 72 + nt * 16 + pos] =
                        (_Float16)fmaxf(accA[mt][nt][r], 0.f);
        h8 aH[2][2];
        #pragma unroll
        for (int mt = 0; mt < 2; ++mt)
            #pragma unroll
            for (int ks = 0; ks < 2; ++ks)
                aH[mt][ks] = *(const h8*)(P + (mt * 16 + pos) * 72 + ks * 32 + quad * 8);
        // stage B: acc2 += h1chunk @ W2chunk^T
        const _Float16* W2L = W2c + cb * 4608;
        #pragma unroll
        for (int ks = 0; ks < 2; ++ks)
            #pragma unroll
            for (int cm = 0; cm < 4; ++cm) {
                h8 bf = *(const h8*)(W2L + (cm * 16 + pos) * 72 + ks * 32 + quad * 8);
                acc2[0][cm] = MFMA(aH[0][ks], bf, acc2[0][cm], 0, 0, 0);
                acc2[1][cm] = MFMA(aH[1][ks], bf, acc2[1][cm], 0, 0, 0);
            }
        if (c < 7) {
            cvt_store16(W1c + (cb ^ 1) * 4608 + trow * 72 + tcol, p1);
            cvt_store16(W2c + (cb ^ 1) * 4608 + trow * 72 + tcol, p2);
        }
        __syncthreads();
    }

    // ---- r1 -> own LDS (relu), read back as A-frags ----
    #pragma unroll
    for (int mt = 0; mt < 2; ++mt)
        #pragma unroll
        for (int cm = 0; cm < 4; ++cm)
            #pragma unroll
            for (int r = 0; r < 4; ++r)
                P[(mt * 16 + quad * 4 + r) * 72 + cm * 16 + pos] =
                    (_Float16)fmaxf(acc2[mt][cm][r], 0.f);
    h8 aR[2][2];
    #pragma unroll
    for (int mt = 0; mt < 2; ++mt)
        #pragma unroll
        for (int ks = 0; ks < 2; ++ks)
            aR[mt][ks] = *(const h8*)(P + (mt * 16 + pos) * 72 + ks * 32 + quad * 8);
    // fold A-frag: k=64 -> xn, k=65 -> 1 (only quad 0 lanes carry data)
    h8 af3[2];
    #pragma unroll
    for (int mt = 0; mt < 2; ++mt) {
        h8 h;
        #pragma unroll
        for (int j = 0; j < 8; ++j) h[j] = (_Float16)0.f;
        if (quad == 0) { h[0] = (_Float16)xns[wrow + mt * 16 + pos]; h[1] = (_Float16)1.f; }
        af3[mt] = h;
    }

    // ---- stage C/D over 8 h-chunks: W3 staged into W1c dbuf ----
    {
        float4 p3[4];
        #pragma unroll
        for (int q = 0; q < 4; ++q) p3[q] = *(const float4*)(W3n + (size_t)trow * 128 + tcol + q * 4);
        cvt_store16(W1c + trow * 72 + tcol, p3);
    }
    __syncthreads();

    float o[2][4] = {};
    for (int c = 0; c < 8; ++c) {
        const int cb = c & 1;
        const int hc = c << 6;
        float4 p3[4];
        if (c < 7) {
            #pragma unroll
            for (int q = 0; q < 4; ++q)
                p3[q] = *(const float4*)(W3n + (size_t)(hc + 64 + trow) * 128 + tcol + q * 4);
        }
        const _Float16* W3L = W1c + cb * 4608;
        fx4 acc3[2][4] = {};
        #pragma unroll
        for (int ks = 0; ks < 2; ++ks)
            #pragma unroll
            for (int nt = 0; nt < 4; ++nt) {
                h8 bf = *(const h8*)(W3L + (nt * 16 + pos) * 72 + ks * 32 + quad * 8);
                acc3[0][nt] = MFMA(aR[0][ks], bf, acc3[0][nt], 0, 0, 0);
                acc3[1][nt] = MFMA(aR[1][ks], bf, acc3[1][nt], 0, 0, 0);
            }
        // fold: += [xn,1] @ [w3c; b3]
        #pragma unroll
        for (int nt = 0; nt < 4; ++nt) {
            h8 bf3;
            #pragma unroll
            for (int j = 0; j < 8; ++j) bf3[j] = (_Float16)0.f;
            if (quad == 0) {
                const int h = hc + nt * 16 + pos;
                bf3[0] = (_Float16)w3cs[h];
                bf3[1] = (_Float16)b3s[h];
            }
            acc3[0][nt] = MFMA(af3[0], bf3, acc3[0][nt], 0, 0, 0);
            acc3[1][nt] = MFMA(af3[1], bf3, acc3[1][nt], 0, 0, 0);
        }
        // relu + W4 dot
        #pragma unroll
        for (int nt = 0; nt < 4; ++nt) {
            const float w4v = w4s[hc + nt * 16 + pos];
            #pragma unroll
            for (int mt = 0; mt < 2; ++mt)
                #pragma unroll
                for (int r = 0; r < 4; ++r)
                    o[mt][r] = fmaf(fmaxf(acc3[mt][nt][r], 0.f), w4v, o[mt][r]);
        }
        if (c < 7) cvt_store16(W1c + (cb ^ 1) * 4608 + trow * 72 + tcol, p3);
        __syncthreads();
    }

    // ---- reduce over the 16 h-columns (pos bits), store ----
    #pragma unroll
    for (int m = 1; m < 16; m <<= 1)
        #pragma unroll
        for (int mt = 0; mt < 2; ++mt)
            #pragma unroll
            for (int r = 0; r < 4; ++r)
                o[mt][r] += __shfl_xor(o[mt][r], m, 64);

    if (pos == 0) {
        const float bb = b4[n];
        #pragma unroll
        for (int mt = 0; mt < 2; ++mt)
            #pragma unroll
            for (int r = 0; r < 4; ++r) {
                const int row = row0 + wrow + mt * 16 + quad * 4 + r;
                out[(size_t)row * 64 + n] = fmaxf(o[mt][r] + bb, 0.f);
            }
    }
}

extern "C" void kernel_launch(void* const* d_in, const int* in_sizes, int n_in,
                              void* d_out, int out_size, void* d_ws, size_t ws_size,
                              hipStream_t stream)
{
    const float* x  = (const float*)d_in[0];
    const float* W1 = (const float*)d_in[1];
    const float* W2 = (const float*)d_in[2];
    const float* W3 = (const float*)d_in[3];
    const float* b3 = (const float*)d_in[4];
    const float* W4 = (const float*)d_in[5];
    const float* b4 = (const float*)d_in[6];
    float* out = (float*)d_out;
    hipLaunchKernelGGL(causal_mfma3, dim3(512), dim3(256), 0, stream,
                       x, W1, W2, W3, b3, W4, b4, out);
}